// Round 4
// 1166.301 us; speedup vs baseline: 1.0173x; 1.0173x over previous
//
#include <hip/hip_runtime.h>
#include <stdint.h>

// WindowAttention (Swin, 7x7, C=384, H=12, hd=32, B_=4096, nW=64), fp32 in/out.
// Strategy: bf16 MFMA for all three matmul stages (threshold 3.3e-2 allows it).
//   prep      : cast x / qkv_w / proj_w to bf16, expand rpb table to [12][49][49]
//   gemm_nt<0>: qkv = x @ qkv_w^T + b  (q-part scaled), bf16 out  [200704 x 1152]
//   attn      : wave-per-(window,head) attention (padded 49->64), bf16 out
//   gemm_nt<1>: out = attnout @ proj_w^T + b, fp32 out
// M=200704=1568*128, N=1152=9*128 / 384=3*128, K=384=12*32 -> no edge handling.
//
// Round 2 changes (vs 338us gemm0 profile: MfmaUtil 23%, FETCH 636MB vs 155 ideal,
// LDS_BANK_CONFLICT 2.2e7, 64 scalar 2B stores/thread):
//   * XCD-aware bijective block swizzle (T1): the NX col-tiles sharing an A
//     panel now land on ONE XCD's L2 instead of 8 -> A fetched ~once.
//   * chunk-XOR LDS swizzle on A/B tiles (T2, via pre-swizzled global source,
//     rule #21): fragment ds_read_b128 drops 8-way -> 2-way (free).
//   * double-buffered LDS + stage-before-compute, 1 barrier/K-step (T3-min).
//   * epilogue repack via LDS -> 8x16B coalesced stores/thread instead of
//     64 scalar stores (VMEM issue port was saturated by the epilogue).
// (Rounds 2-4 bench attempts hit GPUAcquisitionTimeout; resubmitting unchanged.)

typedef unsigned short u16;
typedef short short8 __attribute__((ext_vector_type(8)));   // 8 x bf16 (4 VGPRs)
typedef float f32x4 __attribute__((ext_vector_type(4)));

static __device__ __forceinline__ u16 f2bf(float f) {
  unsigned u = __builtin_bit_cast(unsigned, f);
  return (u16)((u + 0x7fffu + ((u >> 16) & 1u)) >> 16);
}

// async global->LDS, 16B per lane. LDS dest = wave-uniform base + lane*16.
static __device__ __forceinline__ void async_cp16(const u16* g, u16* l) {
  __builtin_amdgcn_global_load_lds(
      (__attribute__((address_space(1))) unsigned int*)g,
      (__attribute__((address_space(3))) unsigned int*)l, 16, 0, 0);
}

// ---------------------------------------------------------------- prep ------
__global__ __launch_bounds__(256) void prep_kernel(
    const float* __restrict__ x, const float* __restrict__ wq,
    const float* __restrict__ wp, const float* __restrict__ rpt,
    u16* __restrict__ xb, u16* __restrict__ wqb, u16* __restrict__ wpb,
    float* __restrict__ rpbf)
{
  const int bid = blockIdx.x, tid = threadIdx.x;
  if (bid < 1024) {
    const float4* x4 = (const float4*)x;
    ushort4* o4 = (ushort4*)xb;
    for (unsigned i = bid * 256u + tid; i < 19267584u; i += 262144u) {
      float4 v = x4[i];
      ushort4 o; o.x = f2bf(v.x); o.y = f2bf(v.y); o.z = f2bf(v.z); o.w = f2bf(v.w);
      o4[i] = o;
    }
  } else if (bid < 1088) {
    for (unsigned i = (bid - 1024) * 256u + tid; i < 147456u; i += 16384u) {
      if (i < 110592u) {
        float4 v = ((const float4*)wq)[i];
        ushort4 o; o.x = f2bf(v.x); o.y = f2bf(v.y); o.z = f2bf(v.z); o.w = f2bf(v.w);
        ((ushort4*)wqb)[i] = o;
      } else {
        unsigned k = i - 110592u;
        float4 v = ((const float4*)wp)[k];
        ushort4 o; o.x = f2bf(v.x); o.y = f2bf(v.y); o.z = f2bf(v.z); o.w = f2bf(v.w);
        ((ushort4*)wpb)[k] = o;
      }
    }
  } else {
    for (int e = (bid - 1088) * 256 + tid; e < 28812; e += 2048) {
      int h = e / 2401, r2 = e - h * 2401;
      int i = r2 / 49, j = r2 - (r2 / 49) * 49;
      int rel = (i / 7 - j / 7 + 6) * 13 + (i % 7 - j % 7 + 6);
      rpbf[e] = rpt[rel * 12 + h];
    }
  }
}

// ------------------------------------------------------------- NT GEMM ------
// C[M][NTOT] = A[M][384] @ Bw[NTOT][384]^T + bias, 128x128 tile / block.
// LDS tile swizzle: row r of a [*][32]-u16 tile stores global 8-u16 chunk g at
// slot g ^ ((r>>1)&3). Staged with linear-dest global_load_lds by swizzling
// the per-lane SOURCE column; fragment reads apply the same XOR -> 2-way banks.
template <int MODE>
__global__ __launch_bounds__(256) void gemm_nt(
    const u16* __restrict__ A, const u16* __restrict__ Bw,
    const float* __restrict__ bias, void* __restrict__ Cp)
{
  constexpr int NTOT = (MODE == 0) ? 1152 : 384;
  constexpr int NX = NTOT / 128;                 // 9 or 3 col-tiles
  constexpr int CPX = (NX * 1568) / 8;           // blocks per XCD (exact)
  __shared__ u16 smem[16384];                    // 2 x (As 4096 | Bs 4096) u16

  const int tid = threadIdx.x;
  const int wave = tid >> 6, lane = tid & 63;
  const int lr = lane & 15, quad = lane >> 4;

  // XCD-aware bijective swizzle: dispatch d -> XCD d%8; give XCD k the
  // contiguous logical range [k*CPX,(k+1)*CPX). NX divides CPX, so all NX
  // col-tiles sharing one A panel stay on one XCD.
  const int lid = (blockIdx.x & 7) * CPX + (blockIdx.x >> 3);
  const int by = lid / NX;
  const int bx = lid - by * NX;
  const int m0 = by * 128, n0 = bx * 128;
  const int wm = (wave & 1) * 64, wn = (wave >> 1) * 64;

  // staging geometry: lane covers tile row r4 = tid/4, chunk c0 = tid&3;
  // source column chunk = c0 ^ ((r4>>1)&3)  (LDS dest stays linear).
  const int r4 = tid >> 2;
  const int cs = ((tid & 3) ^ ((r4 >> 1) & 3)) * 8;
  const size_t ga0 = (size_t)(m0 + r4) * 384 + cs;
  const size_t ga1 = (size_t)(m0 + 64 + r4) * 384 + cs;
  const size_t gb0 = (size_t)(n0 + r4) * 384 + cs;
  const size_t gb1 = (size_t)(n0 + 64 + r4) * 384 + cs;

  f32x4 acc[4][4] = {};
  const int sw = (lr >> 1) & 3;                  // = (row>>1)&3 for row=..+lr

  // prologue: stage K-step 0 into buffer 0
  {
    u16* As = smem; u16* Bs = smem + 4096;
    async_cp16(&A[ga0], As + wave * 512);
    async_cp16(&A[ga1], As + 2048 + wave * 512);
    async_cp16(&Bw[gb0], Bs + wave * 512);
    async_cp16(&Bw[gb1], Bs + 2048 + wave * 512);
  }
  __syncthreads();

  int buf = 0;
#pragma unroll 2
  for (int it = 0; it < 12; ++it) {
    u16* As = smem + buf * 8192;
    u16* Bs = As + 4096;
    if (it < 11) {                               // stage next K-step early
      u16* An = smem + (buf ^ 1) * 8192;
      u16* Bn = An + 4096;
      const int k0 = (it + 1) * 32;
      async_cp16(&A[ga0 + k0], An + wave * 512);
      async_cp16(&A[ga1 + k0], An + 2048 + wave * 512);
      async_cp16(&Bw[gb0 + k0], Bn + wave * 512);
      async_cp16(&Bw[gb1 + k0], Bn + 2048 + wave * 512);
    }
    short8 af[4], bf[4];
#pragma unroll
    for (int mi = 0; mi < 4; ++mi)
      af[mi] = *(const short8*)&As[(wm + mi * 16 + lr) * 32 + ((quad ^ sw) * 8)];
#pragma unroll
    for (int ni = 0; ni < 4; ++ni)
      bf[ni] = *(const short8*)&Bs[(wn + ni * 16 + lr) * 32 + ((quad ^ sw) * 8)];
#pragma unroll
    for (int mi = 0; mi < 4; ++mi)
#pragma unroll
      for (int ni = 0; ni < 4; ++ni)
        acc[mi][ni] = __builtin_amdgcn_mfma_f32_16x16x32_bf16(af[mi], bf[ni], acc[mi][ni], 0, 0, 0);
    __syncthreads();                             // drains vm+lgkm: next buf ready,
    buf ^= 1;                                    // cur buf safe to overwrite
  }

  // ---- epilogue: bias(+scale), repack via LDS, coalesced 16B stores ----
  float bv[4];
#pragma unroll
  for (int ni = 0; ni < 4; ++ni) bv[ni] = bias[n0 + wn + ni * 16 + lr];

  if (MODE == 0) {
    // bf16 [128][128] = 32 KB, fits both buffers. chunk-XOR: slot = c8 ^ ((row>>2)&7)
    const float sc = (n0 < 384) ? 0.17677669529663687f : 1.0f;  // q-part scale
    u16* ot = smem;
#pragma unroll
    for (int mi = 0; mi < 4; ++mi)
#pragma unroll
      for (int ni = 0; ni < 4; ++ni)
#pragma unroll
        for (int r = 0; r < 4; ++r) {
          const int row = wm + mi * 16 + quad * 4 + r;
          const int col = wn + ni * 16 + lr;
          const int slot = (col >> 3) ^ ((row >> 2) & 7);
          ot[row * 128 + slot * 8 + (col & 7)] =
              f2bf((acc[mi][ni][r] + bv[ni]) * sc);
        }
    __syncthreads();
    u16* outp = (u16*)Cp;
#pragma unroll
    for (int j = 0; j < 8; ++j) {
      const int cid = j * 256 + tid;
      const int row = cid >> 4, slot = cid & 15;
      const int c8 = slot ^ ((row >> 2) & 7);
      *(short8*)&outp[(size_t)(m0 + row) * NTOT + n0 + c8 * 8] =
          *(const short8*)&ot[row * 128 + slot * 8];
    }
  } else {
    // f32: two 64-row passes of 32 KB. slot = c4 ^ ((lrow>>2)&7)
    float* fl = (float*)smem;                    // [64][128]
    float* outp = (float*)Cp;
#pragma unroll
    for (int h = 0; h < 2; ++h) {
      if ((wave & 1) == h) {                     // waves owning rows h*64..h*64+63
#pragma unroll
        for (int mi = 0; mi < 4; ++mi)
#pragma unroll
          for (int ni = 0; ni < 4; ++ni)
#pragma unroll
            for (int r = 0; r < 4; ++r) {
              const int lrow = mi * 16 + quad * 4 + r;
              const int col = wn + ni * 16 + lr;
              const int slot = (col >> 2) ^ ((lrow >> 2) & 7);
              fl[lrow * 128 + slot * 4 + (col & 3)] = acc[mi][ni][r] + bv[ni];
            }
      }
      __syncthreads();
#pragma unroll
      for (int j = 0; j < 8; ++j) {
        const int cid = j * 256 + tid;
        const int lrow = cid >> 5, slot = cid & 31;
        const int c4 = slot ^ ((lrow >> 2) & 7);
        *(f32x4*)&outp[(size_t)(m0 + h * 64 + lrow) * NTOT + n0 + c4 * 4] =
            *(const f32x4*)&fl[lrow * 128 + slot * 4];
      }
      if (h == 0) __syncthreads();
    }
  }
}

// ------------------------------------------------------------ attention -----
// One WAVE per (window, head): grid 12288 x 256, wave w of block bl handles
// window b = bl/3, head h = (bl%3)*4 + w. No __syncthreads, no head loop.
// QK^T operands straight from global in fragment layout (hd=32 = one K-step).
// rpb + mask added from global (L2/L3-resident, coalesced across lr).
// P and V^T live in per-wave LDS with XOR-swizzled 16B chunks:
//   addr(row, col) = row*64 + ((col>>3 ^ (row&7))*8) + (col&7)   [u16 units]
// -> b128 fragment reads are bank-conflict-free. 12.3KB/wave, 49.2KB/block
// -> 3 blocks/CU (12 waves), matching the ~148-VGPR cap.
__global__ __launch_bounds__(256) void attn_kernel(
    const u16* __restrict__ qkv, const float* __restrict__ mask,
    const float* __restrict__ rpbf, u16* __restrict__ attnout)
{
  __shared__ u16 P_lds[4][64 * 64];
  __shared__ u16 VT_lds[4][32 * 64];
  const int tid = threadIdx.x;
  const int wave = tid >> 6, lane = tid & 63;
  const int lr = lane & 15, quad = lane >> 4;
  // XCD swizzle: the 3 blocks sharing one window's 110 KB of qkv stay on one XCD.
  const int bl = (blockIdx.x & 7) * 1536 + (blockIdx.x >> 3);
  const int b = bl / 3;
  const int h = (bl - b * 3) * 4 + wave;

  const size_t base = (size_t)b * (49 * 1152);
  u16* P  = P_lds[wave];
  u16* Vt = VT_lds[wave];
  const short8 z8 = {0, 0, 0, 0, 0, 0, 0, 0};

  // ---- stage V^T (vectorized 16B loads, swizzled scatter; pad toks zeroed
  //      so LDS garbage (possibly NaN-pattern) never reaches the MFMA) ----
  {
    const int dh = lane & 3;          // 8-d group: d = dh*8 + j
    const int tk0 = lane >> 2;        // tok within pass
#pragma unroll
    for (int p = 0; p < 4; ++p) {
      const int tok = p * 16 + tk0;
      short8 v = z8;
      if (tok < 49)
        v = *(const short8*)&qkv[base + (size_t)tok * 1152 + 768 + h * 32 + dh * 8];
#pragma unroll
      for (int j = 0; j < 8; ++j) {
        const int d = dh * 8 + j;     // d&7 == j
        Vt[d * 64 + (((tok >> 3) ^ j) * 8) + (tok & 7)] = ((const u16*)&v)[j];
      }
    }
  }

  // ---- QK^T ----  A: Q[m=mi*16+lr][k=quad*8+j]   B: K[n=ni*16+lr][k=...]
  short8 qf[4], kf[4];
#pragma unroll
  for (int mi = 0; mi < 4; ++mi) {
    const int row = mi * 16 + lr;
    qf[mi] = (row < 49)
        ? *(const short8*)&qkv[base + (size_t)row * 1152 + h * 32 + quad * 8] : z8;
  }
#pragma unroll
  for (int ni = 0; ni < 4; ++ni) {
    const int tok = ni * 16 + lr;
    kf[ni] = (tok < 49)
        ? *(const short8*)&qkv[base + (size_t)tok * 1152 + 384 + h * 32 + quad * 8] : z8;
  }
  f32x4 s[4][4] = {};
#pragma unroll
  for (int mi = 0; mi < 4; ++mi)
#pragma unroll
    for (int ni = 0; ni < 4; ++ni)
      s[mi][ni] = __builtin_amdgcn_mfma_f32_16x16x32_bf16(qf[mi], kf[ni], s[mi][ni], 0, 0, 0);

  // ---- bias + mask + softmax (quad-local rows), P -> LDS bf16 (swizzled) ----
  const float* rh = &rpbf[h * 2401];
  const float* mw = &mask[(size_t)(b & 63) * 2401];
  float linv[4][4];
#pragma unroll
  for (int mi = 0; mi < 4; ++mi) {
#pragma unroll
    for (int r = 0; r < 4; ++r) {
      const int row = mi * 16 + quad * 4 + r;
      float vals[4];
#pragma unroll
      for (int ni = 0; ni < 4; ++ni) {
        const int col = ni * 16 + lr;
        float v;
        if (row < 49 && col < 49)
          v = s[mi][ni][r] + rh[row * 49 + col] + mw[row * 49 + col];
        else
          v = -1e30f;                 // finite: pad rows -> exp(0), never output
        vals[ni] = v;
      }
      float m = fmaxf(fmaxf(vals[0], vals[1]), fmaxf(vals[2], vals[3]));
      m = fmaxf(m, __shfl_xor(m, 1));
      m = fmaxf(m, __shfl_xor(m, 2));
      m = fmaxf(m, __shfl_xor(m, 4));
      m = fmaxf(m, __shfl_xor(m, 8));
      float l = 0.f;
#pragma unroll
      for (int ni = 0; ni < 4; ++ni) {
        const float p = __expf(vals[ni] - m);
        l += p;
        const int col = ni * 16 + lr;
        P[row * 64 + (((col >> 3) ^ (row & 7)) * 8) + (col & 7)] = f2bf(p);
      }
      l += __shfl_xor(l, 1);
      l += __shfl_xor(l, 2);
      l += __shfl_xor(l, 4);
      l += __shfl_xor(l, 8);
      linv[mi][r] = 1.0f / l;
    }
  }

  // ---- O = P @ V ----  A: P[m=mi*16+lr][k=kh*32+quad*8+j]
  //                      B: VT[n=d=ni*16+lr][k=tok=kh*32+quad*8+j]
  f32x4 o[4][2] = {};
#pragma unroll
  for (int kh = 0; kh < 2; ++kh) {
    const int chunk = (kh * 4 + quad) ^ (lr & 7);   // row&7 == lr&7 for both
    short8 vf[2];
#pragma unroll
    for (int ni = 0; ni < 2; ++ni)
      vf[ni] = *(const short8*)&Vt[(ni * 16 + lr) * 64 + chunk * 8];
#pragma unroll
    for (int mi = 0; mi < 4; ++mi) {
      short8 pf = *(const short8*)&P[(mi * 16 + lr) * 64 + chunk * 8];
#pragma unroll
      for (int ni = 0; ni < 2; ++ni)
        o[mi][ni] = __builtin_amdgcn_mfma_f32_16x16x32_bf16(pf, vf[ni], o[mi][ni], 0, 0, 0);
    }
  }

  // ---- epilogue: attnout[b][row][h*32+d] = O/l, bf16 ----
  u16* outp = attnout + (size_t)b * (49 * 384) + h * 32;
#pragma unroll
  for (int mi = 0; mi < 4; ++mi)
#pragma unroll
    for (int r = 0; r < 4; ++r) {
      const int row = mi * 16 + quad * 4 + r;
      if (row < 49) {
        const float li = linv[mi][r];
#pragma unroll
        for (int ni = 0; ni < 2; ++ni)
          outp[row * 384 + ni * 16 + lr] = f2bf(o[mi][ni][r] * li);
      }
    }
}

// ------------------------------------------------------------- launch -------
extern "C" void kernel_launch(void* const* d_in, const int* in_sizes, int n_in,
                              void* d_out, int out_size, void* d_ws, size_t ws_size,
                              hipStream_t stream) {
  const float* x      = (const float*)d_in[0];
  const float* mask   = (const float*)d_in[1];
  const float* qkv_w  = (const float*)d_in[2];
  const float* qkv_b  = (const float*)d_in[3];
  const float* proj_w = (const float*)d_in[4];
  const float* proj_b = (const float*)d_in[5];
  const float* rpb_t  = (const float*)d_in[6];
  float* out = (float*)d_out;

  // ws layout identical to round 1 (618 MB, proven to fit).
  char* ws = (char*)d_ws;
  u16* qkv    = (u16*)ws;                                    // [200704][1152] bf16
  u16* xb     = (u16*)(ws + 462422016u);                     // [200704][384] bf16
  u16* attnout = xb;                                         // alias (xb dead)
  u16* wqb    = (u16*)(ws + 462422016u + 154140672u);        // [1152][384] bf16
  u16* wpb    = wqb + 442368;                                // [384][384] bf16
  float* rpbf = (float*)((char*)wpb + 294912u);              // [12][49][49] f32

  prep_kernel<<<1096, 256, 0, stream>>>(x, qkv_w, proj_w, rpb_t, xb, wqb, wpb, rpbf);
  gemm_nt<0><<<14112, 256, 0, stream>>>(xb, wqb, qkv_b, (void*)qkv);
  attn_kernel<<<12288, 256, 0, stream>>>(qkv, mask, rpbf, attnout);
  gemm_nt<1><<<4704, 256, 0, stream>>>(attnout, wpb, proj_b, (void*)out);
}

// Round 8
// 1164.728 us; speedup vs baseline: 1.0186x; 1.0014x over previous
//
#include <hip/hip_runtime.h>
#include <stdint.h>

// WindowAttention (Swin, 7x7, C=384, H=12, hd=32, B_=4096, nW=64), fp32 in/out.
//   prep      : cast x / qkv_w (q-rows pre-scaled) / proj_w to bf16,
//               expand rpb table, write pre-scaled qkv bias
//   gemm_nt<0>: qkv = x @ qkv_w^T + b, bf16 out  [200704 x 1152]
//   attn      : wave-per-(window,head) attention (padded 49->64), bf16 out
//   gemm_nt<1>: out = attnout @ proj_w^T + b, fp32 out
//
// Round 7: round-5's counted-vmcnt 3-buffer pipeline RACED (first-run absmax
// 0.21, replay 468 -> nondeterministic). REVERTED to the round-4 proven
// 2-buffer full-drain K-loop (stage -> compute -> __syncthreads per step).
// KEPT from round 5 (numerically bounded, attributable as one small diff):
//   * q-scale folded into prep (wq rows + bias pre-scaled)
//   * MODE-0 epilogue bf16 conversion via v_cvt_pk_bf16_f32 pairs
// (Round 8: GPUAcquisitionTimeout on round-7 attempt; resubmitting unchanged.)

typedef unsigned short u16;
typedef short short8 __attribute__((ext_vector_type(8)));   // 8 x bf16 (4 VGPRs)
typedef float f32x4 __attribute__((ext_vector_type(4)));

static __device__ __forceinline__ u16 f2bf(float f) {
  unsigned u = __builtin_bit_cast(unsigned, f);
  return (u16)((u + 0x7fffu + ((u >> 16) & 1u)) >> 16);
}

// pack 2 f32 -> 2 bf16 (RNE), lo = a, hi = b
static __device__ __forceinline__ unsigned cvt_pk_bf16(float a, float b) {
  unsigned r;
  asm("v_cvt_pk_bf16_f32 %0, %1, %2" : "=v"(r) : "v"(a), "v"(b));
  return r;
}

// async global->LDS, 16B per lane. LDS dest = wave-uniform base + lane*16.
static __device__ __forceinline__ void async_cp16(const u16* g, u16* l) {
  __builtin_amdgcn_global_load_lds(
      (__attribute__((address_space(1))) unsigned int*)g,
      (__attribute__((address_space(3))) unsigned int*)l, 16, 0, 0);
}

// ---------------------------------------------------------------- prep ------
__global__ __launch_bounds__(256) void prep_kernel(
    const float* __restrict__ x, const float* __restrict__ wq,
    const float* __restrict__ wp, const float* __restrict__ rpt,
    const float* __restrict__ qb,
    u16* __restrict__ xb, u16* __restrict__ wqb, u16* __restrict__ wpb,
    float* __restrict__ rpbf, float* __restrict__ bias_s)
{
  const int bid = blockIdx.x, tid = threadIdx.x;
  const float S = 0.17677669529663687f;          // hd^-0.5
  if (bid < 1024) {
    const float4* x4 = (const float4*)x;
    ushort4* o4 = (ushort4*)xb;
    for (unsigned i = bid * 256u + tid; i < 19267584u; i += 262144u) {
      float4 v = x4[i];
      ushort4 o; o.x = f2bf(v.x); o.y = f2bf(v.y); o.z = f2bf(v.z); o.w = f2bf(v.w);
      o4[i] = o;
    }
  } else if (bid < 1088) {
    for (unsigned i = (bid - 1024) * 256u + tid; i < 147456u; i += 16384u) {
      if (i < 110592u) {
        float4 v = ((const float4*)wq)[i];
        const float s = (i < 36864u) ? S : 1.0f;   // rows 0..383 = q-part
        ushort4 o; o.x = f2bf(v.x * s); o.y = f2bf(v.y * s);
        o.z = f2bf(v.z * s); o.w = f2bf(v.w * s);
        ((ushort4*)wqb)[i] = o;
      } else {
        unsigned k = i - 110592u;
        float4 v = ((const float4*)wp)[k];
        ushort4 o; o.x = f2bf(v.x); o.y = f2bf(v.y); o.z = f2bf(v.z); o.w = f2bf(v.w);
        ((ushort4*)wpb)[k] = o;
      }
    }
  } else {
    for (int e = (bid - 1088) * 256 + tid; e < 28812 + 1152; e += 2048) {
      if (e < 28812) {
        int h = e / 2401, r2 = e - h * 2401;
        int i = r2 / 49, j = r2 - (r2 / 49) * 49;
        int rel = (i / 7 - j / 7 + 6) * 13 + (i % 7 - j % 7 + 6);
        rpbf[e] = rpt[rel * 12 + h];
      } else {
        int c = e - 28812;
        bias_s[c] = qb[c] * ((c < 384) ? S : 1.0f);
      }
    }
  }
}

// ------------------------------------------------------------- NT GEMM ------
// C[M][NTOT] = A[M][384] @ Bw[NTOT][384]^T + bias, 128x128 tile / block.
// Round-4 proven loop: 2-buffer LDS, stage(next) -> compute(cur) ->
// __syncthreads (full drain) per K-step. Chunk-XOR LDS swizzle via
// pre-swizzled global source (rule #21).
template <int MODE>
__global__ __launch_bounds__(256) void gemm_nt(
    const u16* __restrict__ A, const u16* __restrict__ Bw,
    const float* __restrict__ bias, void* __restrict__ Cp)
{
  constexpr int NTOT = (MODE == 0) ? 1152 : 384;
  constexpr int NX = NTOT / 128;                 // 9 or 3 col-tiles
  constexpr int CPX = (NX * 1568) / 8;           // blocks per XCD (exact)
  __shared__ u16 smem[16384];                    // 2 x (As 4096 | Bs 4096) u16

  const int tid = threadIdx.x;
  const int wave = tid >> 6, lane = tid & 63;
  const int lr = lane & 15, quad = lane >> 4;

  // XCD-aware bijective swizzle: all NX col-tiles of an A panel on one XCD.
  const int lid = (blockIdx.x & 7) * CPX + (blockIdx.x >> 3);
  const int by = lid / NX;
  const int bx = lid - by * NX;
  const int m0 = by * 128, n0 = bx * 128;
  const int wm = (wave & 1) * 64, wn = (wave >> 1) * 64;

  // staging geometry: lane covers tile row r4 = tid/4, chunk c0 = tid&3;
  // source column chunk = c0 ^ ((r4>>1)&3)  (LDS dest stays linear).
  const int r4 = tid >> 2;
  const int cs = ((tid & 3) ^ ((r4 >> 1) & 3)) * 8;
  const size_t ga0 = (size_t)(m0 + r4) * 384 + cs;
  const size_t ga1 = (size_t)(m0 + 64 + r4) * 384 + cs;
  const size_t gb0 = (size_t)(n0 + r4) * 384 + cs;
  const size_t gb1 = (size_t)(n0 + 64 + r4) * 384 + cs;

  f32x4 acc[4][4] = {};
  const int sw = (lr >> 1) & 3;                  // = (row>>1)&3 for row=..+lr

  // prologue: stage K-step 0 into buffer 0
  {
    u16* As = smem; u16* Bs = smem + 4096;
    async_cp16(&A[ga0], As + wave * 512);
    async_cp16(&A[ga1], As + 2048 + wave * 512);
    async_cp16(&Bw[gb0], Bs + wave * 512);
    async_cp16(&Bw[gb1], Bs + 2048 + wave * 512);
  }
  __syncthreads();

  int buf = 0;
#pragma unroll 2
  for (int it = 0; it < 12; ++it) {
    u16* As = smem + buf * 8192;
    u16* Bs = As + 4096;
    if (it < 11) {                               // stage next K-step early
      u16* An = smem + (buf ^ 1) * 8192;
      u16* Bn = An + 4096;
      const int k0 = (it + 1) * 32;
      async_cp16(&A[ga0 + k0], An + wave * 512);
      async_cp16(&A[ga1 + k0], An + 2048 + wave * 512);
      async_cp16(&Bw[gb0 + k0], Bn + wave * 512);
      async_cp16(&Bw[gb1 + k0], Bn + 2048 + wave * 512);
    }
    short8 af[4], bf[4];
#pragma unroll
    for (int mi = 0; mi < 4; ++mi)
      af[mi] = *(const short8*)&As[(wm + mi * 16 + lr) * 32 + ((quad ^ sw) * 8)];
#pragma unroll
    for (int ni = 0; ni < 4; ++ni)
      bf[ni] = *(const short8*)&Bs[(wn + ni * 16 + lr) * 32 + ((quad ^ sw) * 8)];
#pragma unroll
    for (int mi = 0; mi < 4; ++mi)
#pragma unroll
      for (int ni = 0; ni < 4; ++ni)
        acc[mi][ni] = __builtin_amdgcn_mfma_f32_16x16x32_bf16(af[mi], bf[ni], acc[mi][ni], 0, 0, 0);
    __syncthreads();                             // drains vm+lgkm: next buf ready,
    buf ^= 1;                                    // cur buf safe to overwrite
  }

  // ---- epilogue: bias, repack via LDS, coalesced 16B stores ----
  float bv[4];
#pragma unroll
  for (int ni = 0; ni < 4; ++ni) bv[ni] = bias[n0 + wn + ni * 16 + lr];

  if (MODE == 0) {
    // bf16 [128][128] = 32 KB fills both buffers. chunk-XOR: slot = c8 ^ ((row>>2)&7)
    // (q-scale already folded into wqb/bias_s by prep; conversion via cvt_pk.)
    u16* ot = smem;
#pragma unroll
    for (int mi = 0; mi < 4; ++mi)
#pragma unroll
      for (int ni = 0; ni < 4; ++ni) {
        const int row0 = wm + mi * 16 + quad * 4;      // multiple of 4
        const int col = wn + ni * 16 + lr;
        const int slot = (col >> 3) ^ ((row0 >> 2) & 7);
        u16* dst = &ot[row0 * 128 + slot * 8 + (col & 7)];
        const unsigned p01 = cvt_pk_bf16(acc[mi][ni][0] + bv[ni], acc[mi][ni][1] + bv[ni]);
        const unsigned p23 = cvt_pk_bf16(acc[mi][ni][2] + bv[ni], acc[mi][ni][3] + bv[ni]);
        dst[0]   = (u16)p01; dst[128] = (u16)(p01 >> 16);
        dst[256] = (u16)p23; dst[384] = (u16)(p23 >> 16);
      }
    __syncthreads();
    u16* outp = (u16*)Cp;
#pragma unroll
    for (int j = 0; j < 8; ++j) {
      const int cid = j * 256 + tid;
      const int row = cid >> 4, slot = cid & 15;
      const int c8 = slot ^ ((row >> 2) & 7);
      *(short8*)&outp[(size_t)(m0 + row) * NTOT + n0 + c8 * 8] =
          *(const short8*)&ot[row * 128 + slot * 8];
    }
  } else {
    // f32: two 64-row passes of 32 KB. slot = c4 ^ ((lrow>>2)&7)
    float* fl = (float*)smem;                    // [64][128]
    float* outp = (float*)Cp;
#pragma unroll
    for (int h = 0; h < 2; ++h) {
      if ((wave & 1) == h) {                     // waves owning rows h*64..h*64+63
#pragma unroll
        for (int mi = 0; mi < 4; ++mi)
#pragma unroll
          for (int ni = 0; ni < 4; ++ni)
#pragma unroll
            for (int r = 0; r < 4; ++r) {
              const int lrow = mi * 16 + quad * 4 + r;
              const int col = wn + ni * 16 + lr;
              const int slot = (col >> 2) ^ ((lrow >> 2) & 7);
              fl[lrow * 128 + slot * 4 + (col & 3)] = acc[mi][ni][r] + bv[ni];
            }
      }
      __syncthreads();
#pragma unroll
      for (int j = 0; j < 8; ++j) {
        const int cid = j * 256 + tid;
        const int lrow = cid >> 5, slot = cid & 31;
        const int c4 = slot ^ ((lrow >> 2) & 7);
        *(f32x4*)&outp[(size_t)(m0 + h * 64 + lrow) * NTOT + n0 + c4 * 4] =
            *(const f32x4*)&fl[lrow * 128 + slot * 4];
      }
      if (h == 0) __syncthreads();
    }
  }
}

// ------------------------------------------------------------ attention -----
// One WAVE per (window, head): grid 12288 x 256 (unchanged this round).
__global__ __launch_bounds__(256) void attn_kernel(
    const u16* __restrict__ qkv, const float* __restrict__ mask,
    const float* __restrict__ rpbf, u16* __restrict__ attnout)
{
  __shared__ u16 P_lds[4][64 * 64];
  __shared__ u16 VT_lds[4][32 * 64];
  const int tid = threadIdx.x;
  const int wave = tid >> 6, lane = tid & 63;
  const int lr = lane & 15, quad = lane >> 4;
  // XCD swizzle: the 3 blocks sharing one window's 110 KB of qkv stay on one XCD.
  const int bl = (blockIdx.x & 7) * 1536 + (blockIdx.x >> 3);
  const int b = bl / 3;
  const int h = (bl - b * 3) * 4 + wave;

  const size_t base = (size_t)b * (49 * 1152);
  u16* P  = P_lds[wave];
  u16* Vt = VT_lds[wave];
  const short8 z8 = {0, 0, 0, 0, 0, 0, 0, 0};

  // ---- stage V^T (vectorized 16B loads, swizzled scatter; pad toks zeroed) --
  {
    const int dh = lane & 3;          // 8-d group: d = dh*8 + j
    const int tk0 = lane >> 2;        // tok within pass
#pragma unroll
    for (int p = 0; p < 4; ++p) {
      const int tok = p * 16 + tk0;
      short8 v = z8;
      if (tok < 49)
        v = *(const short8*)&qkv[base + (size_t)tok * 1152 + 768 + h * 32 + dh * 8];
#pragma unroll
      for (int j = 0; j < 8; ++j) {
        const int d = dh * 8 + j;     // d&7 == j
        Vt[d * 64 + (((tok >> 3) ^ j) * 8) + (tok & 7)] = ((const u16*)&v)[j];
      }
    }
  }

  // ---- QK^T ----  A: Q[m=mi*16+lr][k=quad*8+j]   B: K[n=ni*16+lr][k=...]
  short8 qf[4], kf[4];
#pragma unroll
  for (int mi = 0; mi < 4; ++mi) {
    const int row = mi * 16 + lr;
    qf[mi] = (row < 49)
        ? *(const short8*)&qkv[base + (size_t)row * 1152 + h * 32 + quad * 8] : z8;
  }
#pragma unroll
  for (int ni = 0; ni < 4; ++ni) {
    const int tok = ni * 16 + lr;
    kf[ni] = (tok < 49)
        ? *(const short8*)&qkv[base + (size_t)tok * 1152 + 384 + h * 32 + quad * 8] : z8;
  }
  f32x4 s[4][4] = {};
#pragma unroll
  for (int mi = 0; mi < 4; ++mi)
#pragma unroll
    for (int ni = 0; ni < 4; ++ni)
      s[mi][ni] = __builtin_amdgcn_mfma_f32_16x16x32_bf16(qf[mi], kf[ni], s[mi][ni], 0, 0, 0);

  // ---- bias + mask + softmax (quad-local rows), P -> LDS bf16 (swizzled) ----
  const float* rh = &rpbf[h * 2401];
  const float* mw = &mask[(size_t)(b & 63) * 2401];
  float linv[4][4];
#pragma unroll
  for (int mi = 0; mi < 4; ++mi) {
#pragma unroll
    for (int r = 0; r < 4; ++r) {
      const int row = mi * 16 + quad * 4 + r;
      float vals[4];
#pragma unroll
      for (int ni = 0; ni < 4; ++ni) {
        const int col = ni * 16 + lr;
        float v;
        if (row < 49 && col < 49)
          v = s[mi][ni][r] + rh[row * 49 + col] + mw[row * 49 + col];
        else
          v = -1e30f;                 // finite: pad rows -> exp(0), never output
        vals[ni] = v;
      }
      float m = fmaxf(fmaxf(vals[0], vals[1]), fmaxf(vals[2], vals[3]));
      m = fmaxf(m, __shfl_xor(m, 1));
      m = fmaxf(m, __shfl_xor(m, 2));
      m = fmaxf(m, __shfl_xor(m, 4));
      m = fmaxf(m, __shfl_xor(m, 8));
      float l = 0.f;
#pragma unroll
      for (int ni = 0; ni < 4; ++ni) {
        const float p = __expf(vals[ni] - m);
        l += p;
        const int col = ni * 16 + lr;
        P[row * 64 + (((col >> 3) ^ (row & 7)) * 8) + (col & 7)] = f2bf(p);
      }
      l += __shfl_xor(l, 1);
      l += __shfl_xor(l, 2);
      l += __shfl_xor(l, 4);
      l += __shfl_xor(l, 8);
      linv[mi][r] = 1.0f / l;
    }
  }

  // ---- O = P @ V ----
  f32x4 o[4][2] = {};
#pragma unroll
  for (int kh = 0; kh < 2; ++kh) {
    const int chunk = (kh * 4 + quad) ^ (lr & 7);   // row&7 == lr&7 for both
    short8 vf[2];
#pragma unroll
    for (int ni = 0; ni < 2; ++ni)
      vf[ni] = *(const short8*)&Vt[(ni * 16 + lr) * 64 + chunk * 8];
#pragma unroll
    for (int mi = 0; mi < 4; ++mi) {
      short8 pf = *(const short8*)&P[(mi * 16 + lr) * 64 + chunk * 8];
#pragma unroll
      for (int ni = 0; ni < 2; ++ni)
        o[mi][ni] = __builtin_amdgcn_mfma_f32_16x16x32_bf16(pf, vf[ni], o[mi][ni], 0, 0, 0);
    }
  }

  // ---- epilogue: attnout[b][row][h*32+d] = O/l, bf16 ----
  u16* outp = attnout + (size_t)b * (49 * 384) + h * 32;
#pragma unroll
  for (int mi = 0; mi < 4; ++mi)
#pragma unroll
    for (int r = 0; r < 4; ++r) {
      const int row = mi * 16 + quad * 4 + r;
      if (row < 49) {
        const float li = linv[mi][r];
#pragma unroll
        for (int ni = 0; ni < 2; ++ni)
          outp[row * 384 + ni * 16 + lr] = f2bf(o[mi][ni][r] * li);
      }
    }
}

// ------------------------------------------------------------- launch -------
extern "C" void kernel_launch(void* const* d_in, const int* in_sizes, int n_in,
                              void* d_out, int out_size, void* d_ws, size_t ws_size,
                              hipStream_t stream) {
  const float* x      = (const float*)d_in[0];
  const float* mask   = (const float*)d_in[1];
  const float* qkv_w  = (const float*)d_in[2];
  const float* qkv_b  = (const float*)d_in[3];
  const float* proj_w = (const float*)d_in[4];
  const float* proj_b = (const float*)d_in[5];
  const float* rpb_t  = (const float*)d_in[6];
  float* out = (float*)d_out;

  // ws layout (618 MB + 4.6 KB bias_s).
  char* ws = (char*)d_ws;
  u16* qkv    = (u16*)ws;                                    // [200704][1152] bf16
  u16* xb     = (u16*)(ws + 462422016u);                     // [200704][384] bf16
  u16* attnout = xb;                                         // alias (xb dead)
  u16* wqb    = (u16*)(ws + 462422016u + 154140672u);        // [1152][384] bf16
  u16* wpb    = wqb + 442368;                                // [384][384] bf16
  float* rpbf = (float*)((char*)wpb + 294912u);              // [12][49][49] f32
  float* bias_s = (float*)((char*)rpbf + 115248u);           // [1152] f32 (scaled)

  prep_kernel<<<1096, 256, 0, stream>>>(x, qkv_w, proj_w, rpb_t, qkv_b,
                                        xb, wqb, wpb, rpbf, bias_s);
  gemm_nt<0><<<14112, 256, 0, stream>>>(xb, wqb, bias_s, (void*)qkv);
  attn_kernel<<<12288, 256, 0, stream>>>(qkv, mask, rpbf, attnout);
  gemm_nt<1><<<4704, 256, 0, stream>>>(attnout, wpb, proj_b, (void*)out);
}

// Round 9
// 1134.891 us; speedup vs baseline: 1.0454x; 1.0263x over previous
//
#include <hip/hip_runtime.h>
#include <stdint.h>

// WindowAttention (Swin, 7x7, C=384, H=12, hd=32, B_=4096, nW=64), fp32 in/out.
//   prep      : cast x / qkv_w (q-rows pre-scaled) / proj_w to bf16,
//               expand rpb table, write pre-scaled qkv bias
//   gemm_nt<0>: qkv = x @ qkv_w^T + b, bf16 out  [200704 x 1152]
//   attn      : wave-per-(window,head) attention (padded 49->64), bf16 out
//   gemm_nt<1>: out = attnout @ proj_w^T + b, fp32 out
//
// Round 9 (vs 306us gemm0: MfmaUtil 26%, VALU 41%, Occ 33%; drain-stall
// bound, counted-vmcnt rewrite raced on HW in round 5 -> parameter lane only):
//   * gemm tile 128x128 -> 256x128, 512 threads (8 waves, 4Mx2N of 64x64).
//     Same PROVEN full-drain 2-buffer K-loop; half the barriers per FLOP,
//     2x MFMA per block per barrier, 48KB LDS dbuf, launch_bounds(512,4).
//   * epilogues: 2x128-row (bf16) / 4x64-row (f32) LDS repack passes,
//     identical swizzle pattern, pass-local rows.

typedef unsigned short u16;
typedef short short8 __attribute__((ext_vector_type(8)));   // 8 x bf16 (4 VGPRs)
typedef float f32x4 __attribute__((ext_vector_type(4)));

static __device__ __forceinline__ u16 f2bf(float f) {
  unsigned u = __builtin_bit_cast(unsigned, f);
  return (u16)((u + 0x7fffu + ((u >> 16) & 1u)) >> 16);
}

// pack 2 f32 -> 2 bf16 (RNE), lo = a, hi = b
static __device__ __forceinline__ unsigned cvt_pk_bf16(float a, float b) {
  unsigned r;
  asm("v_cvt_pk_bf16_f32 %0, %1, %2" : "=v"(r) : "v"(a), "v"(b));
  return r;
}

// async global->LDS, 16B per lane. LDS dest = wave-uniform base + lane*16.
static __device__ __forceinline__ void async_cp16(const u16* g, u16* l) {
  __builtin_amdgcn_global_load_lds(
      (__attribute__((address_space(1))) unsigned int*)g,
      (__attribute__((address_space(3))) unsigned int*)l, 16, 0, 0);
}

// ---------------------------------------------------------------- prep ------
__global__ __launch_bounds__(256) void prep_kernel(
    const float* __restrict__ x, const float* __restrict__ wq,
    const float* __restrict__ wp, const float* __restrict__ rpt,
    const float* __restrict__ qb,
    u16* __restrict__ xb, u16* __restrict__ wqb, u16* __restrict__ wpb,
    float* __restrict__ rpbf, float* __restrict__ bias_s)
{
  const int bid = blockIdx.x, tid = threadIdx.x;
  const float S = 0.17677669529663687f;          // hd^-0.5
  if (bid < 1024) {
    const float4* x4 = (const float4*)x;
    ushort4* o4 = (ushort4*)xb;
    for (unsigned i = bid * 256u + tid; i < 19267584u; i += 262144u) {
      float4 v = x4[i];
      ushort4 o; o.x = f2bf(v.x); o.y = f2bf(v.y); o.z = f2bf(v.z); o.w = f2bf(v.w);
      o4[i] = o;
    }
  } else if (bid < 1088) {
    for (unsigned i = (bid - 1024) * 256u + tid; i < 147456u; i += 16384u) {
      if (i < 110592u) {
        float4 v = ((const float4*)wq)[i];
        const float s = (i < 36864u) ? S : 1.0f;   // rows 0..383 = q-part
        ushort4 o; o.x = f2bf(v.x * s); o.y = f2bf(v.y * s);
        o.z = f2bf(v.z * s); o.w = f2bf(v.w * s);
        ((ushort4*)wqb)[i] = o;
      } else {
        unsigned k = i - 110592u;
        float4 v = ((const float4*)wp)[k];
        ushort4 o; o.x = f2bf(v.x); o.y = f2bf(v.y); o.z = f2bf(v.z); o.w = f2bf(v.w);
        ((ushort4*)wpb)[k] = o;
      }
    }
  } else {
    for (int e = (bid - 1088) * 256 + tid; e < 28812 + 1152; e += 2048) {
      if (e < 28812) {
        int h = e / 2401, r2 = e - h * 2401;
        int i = r2 / 49, j = r2 - (r2 / 49) * 49;
        int rel = (i / 7 - j / 7 + 6) * 13 + (i % 7 - j % 7 + 6);
        rpbf[e] = rpt[rel * 12 + h];
      } else {
        int c = e - 28812;
        bias_s[c] = qb[c] * ((c < 384) ? S : 1.0f);
      }
    }
  }
}

// ------------------------------------------------------------- NT GEMM ------
// C[M][NTOT] = A[M][384] @ Bw[NTOT][384]^T + bias, 256x128 tile / block,
// 512 threads = 8 waves (4M x 2N of 64x64 each). Proven full-drain 2-buffer
// K-loop (stage next -> compute cur -> __syncthreads). Chunk-XOR LDS swizzle
// via pre-swizzled global source (rule #21).
template <int MODE>
__global__ __launch_bounds__(512, 4) void gemm_nt(
    const u16* __restrict__ A, const u16* __restrict__ Bw,
    const float* __restrict__ bias, void* __restrict__ Cp)
{
  constexpr int NTOT = (MODE == 0) ? 1152 : 384;
  constexpr int NX = NTOT / 128;                 // 9 or 3 col-tiles
  constexpr int CPX = (NX * 784) / 8;            // blocks per XCD (exact)
  // 2 x (As[256][32] = 8192 u16 | Bs[128][32] = 4096 u16) = 48 KB
  __shared__ u16 smem[24576];

  const int tid = threadIdx.x;
  const int wave = tid >> 6, lane = tid & 63;
  const int lr = lane & 15, quad = lane >> 4;
  const int wr = wave >> 1, wc = wave & 1;       // 4M x 2N sub-tile grid

  // XCD-aware bijective swizzle: all NX col-tiles of an A panel on one XCD.
  const int lid = (blockIdx.x & 7) * CPX + (blockIdx.x >> 3);
  const int by = lid / NX;
  const int bx = lid - by * NX;
  const int m0 = by * 256, n0 = bx * 128;

  // staging geometry: thread covers tile row r = tid/4, chunk c0 = tid&3;
  // source column chunk = c0 ^ ((r>>1)&3)  (LDS dest stays linear).
  const int r = tid >> 2;                        // [0,128)
  const int cs = ((tid & 3) ^ ((r >> 1) & 3)) * 8;
  const size_t ga0 = (size_t)(m0 + r) * 384 + cs;        // A rows [0,128)
  const size_t ga1 = (size_t)(m0 + 128 + r) * 384 + cs;  // A rows [128,256)
  const size_t gb0 = (size_t)(n0 + r) * 384 + cs;        // B rows [0,128)

#define STAGE(BUF, K0)                                                  \
  {                                                                     \
    u16* As_ = smem + (BUF) * 12288;                                    \
    u16* Bs_ = As_ + 8192;                                              \
    async_cp16(&A[ga0 + (K0)], As_ + wave * 512);                       \
    async_cp16(&A[ga1 + (K0)], As_ + 4096 + wave * 512);                \
    async_cp16(&Bw[gb0 + (K0)], Bs_ + wave * 512);                      \
  }

  f32x4 acc[4][4] = {};
  const int sw = (lr >> 1) & 3;                  // = (row>>1)&3 for 16-aligned+lr

  // prologue: stage K-step 0 into buffer 0
  STAGE(0, 0)
  __syncthreads();

  int buf = 0;
#pragma unroll 2
  for (int it = 0; it < 12; ++it) {
    u16* As = smem + buf * 12288;
    u16* Bs = As + 8192;
    if (it < 11) STAGE(buf ^ 1, (it + 1) * 32)   // stage next K-step early
    short8 af[4], bf[4];
#pragma unroll
    for (int mi = 0; mi < 4; ++mi)
      af[mi] = *(const short8*)&As[(wr * 64 + mi * 16 + lr) * 32 + ((quad ^ sw) * 8)];
#pragma unroll
    for (int ni = 0; ni < 4; ++ni)
      bf[ni] = *(const short8*)&Bs[(wc * 64 + ni * 16 + lr) * 32 + ((quad ^ sw) * 8)];
#pragma unroll
    for (int mi = 0; mi < 4; ++mi)
#pragma unroll
      for (int ni = 0; ni < 4; ++ni)
        acc[mi][ni] = __builtin_amdgcn_mfma_f32_16x16x32_bf16(af[mi], bf[ni], acc[mi][ni], 0, 0, 0);
    __syncthreads();                             // drains vm+lgkm: next buf ready,
    buf ^= 1;                                    // cur buf safe to overwrite
  }

  // ---- epilogue: bias, repack via LDS, coalesced 16B stores ----
  float bv[4];
#pragma unroll
  for (int ni = 0; ni < 4; ++ni) bv[ni] = bias[n0 + wc * 64 + ni * 16 + lr];

  if (MODE == 0) {
    // bf16: two 128-row passes of [128][128] u16 = 32 KB. Pass p handles
    // global rows [p*128, p*128+128) (waves with wr>>1 == p).
    u16* ot = smem;
    u16* outp = (u16*)Cp;
#pragma unroll
    for (int p = 0; p < 2; ++p) {
      if ((wr >> 1) == p) {
#pragma unroll
        for (int mi = 0; mi < 4; ++mi)
#pragma unroll
          for (int ni = 0; ni < 4; ++ni) {
            const int row_l = (wr & 1) * 64 + mi * 16 + quad * 4;  // mult of 4
            const int col = wc * 64 + ni * 16 + lr;
            const int slot = (col >> 3) ^ ((row_l >> 2) & 7);
            u16* dst = &ot[row_l * 128 + slot * 8 + (col & 7)];
            const unsigned p01 = cvt_pk_bf16(acc[mi][ni][0] + bv[ni], acc[mi][ni][1] + bv[ni]);
            const unsigned p23 = cvt_pk_bf16(acc[mi][ni][2] + bv[ni], acc[mi][ni][3] + bv[ni]);
            dst[0]   = (u16)p01; dst[128] = (u16)(p01 >> 16);
            dst[256] = (u16)p23; dst[384] = (u16)(p23 >> 16);
          }
      }
      __syncthreads();
#pragma unroll
      for (int j = 0; j < 4; ++j) {
        const int cid = j * 512 + tid;           // [0,2048)
        const int row_l = cid >> 4, slot = cid & 15;
        const int c8 = slot ^ ((row_l >> 2) & 7);
        *(short8*)&outp[(size_t)(m0 + p * 128 + row_l) * NTOT + n0 + c8 * 8] =
            *(const short8*)&ot[row_l * 128 + slot * 8];
      }
      if (p == 0) __syncthreads();
    }
  } else {
    // f32: four 64-row passes of [64][128] f32 = 32 KB. Pass p = waves wr==p.
    float* fl = (float*)smem;
    float* outp = (float*)Cp;
#pragma unroll
    for (int p = 0; p < 4; ++p) {
      if (wr == p) {
#pragma unroll
        for (int mi = 0; mi < 4; ++mi)
#pragma unroll
          for (int ni = 0; ni < 4; ++ni)
#pragma unroll
            for (int rr = 0; rr < 4; ++rr) {
              const int lrow = mi * 16 + quad * 4 + rr;            // [0,64)
              const int col = wc * 64 + ni * 16 + lr;
              const int slot = (col >> 2) ^ ((lrow >> 2) & 7);
              fl[lrow * 128 + slot * 4 + (col & 3)] = acc[mi][ni][rr] + bv[ni];
            }
      }
      __syncthreads();
#pragma unroll
      for (int j = 0; j < 4; ++j) {
        const int cid = j * 512 + tid;           // [0,2048)
        const int lrow = cid >> 5, slot = cid & 31;
        const int c4 = slot ^ ((lrow >> 2) & 7);
        *(f32x4*)&outp[(size_t)(m0 + p * 64 + lrow) * NTOT + n0 + c4 * 4] =
            *(const f32x4*)&fl[lrow * 128 + slot * 4];
      }
      if (p < 3) __syncthreads();
    }
  }
#undef STAGE
}

// ------------------------------------------------------------ attention -----
// One WAVE per (window, head): grid 12288 x 256 (unchanged this round).
__global__ __launch_bounds__(256) void attn_kernel(
    const u16* __restrict__ qkv, const float* __restrict__ mask,
    const float* __restrict__ rpbf, u16* __restrict__ attnout)
{
  __shared__ u16 P_lds[4][64 * 64];
  __shared__ u16 VT_lds[4][32 * 64];
  const int tid = threadIdx.x;
  const int wave = tid >> 6, lane = tid & 63;
  const int lr = lane & 15, quad = lane >> 4;
  // XCD swizzle: the 3 blocks sharing one window's 110 KB of qkv stay on one XCD.
  const int bl = (blockIdx.x & 7) * 1536 + (blockIdx.x >> 3);
  const int b = bl / 3;
  const int h = (bl - b * 3) * 4 + wave;

  const size_t base = (size_t)b * (49 * 1152);
  u16* P  = P_lds[wave];
  u16* Vt = VT_lds[wave];
  const short8 z8 = {0, 0, 0, 0, 0, 0, 0, 0};

  // ---- stage V^T (vectorized 16B loads, swizzled scatter; pad toks zeroed) --
  {
    const int dh = lane & 3;          // 8-d group: d = dh*8 + j
    const int tk0 = lane >> 2;        // tok within pass
#pragma unroll
    for (int p = 0; p < 4; ++p) {
      const int tok = p * 16 + tk0;
      short8 v = z8;
      if (tok < 49)
        v = *(const short8*)&qkv[base + (size_t)tok * 1152 + 768 + h * 32 + dh * 8];
#pragma unroll
      for (int j = 0; j < 8; ++j) {
        const int d = dh * 8 + j;     // d&7 == j
        Vt[d * 64 + (((tok >> 3) ^ j) * 8) + (tok & 7)] = ((const u16*)&v)[j];
      }
    }
  }

  // ---- QK^T ----  A: Q[m=mi*16+lr][k=quad*8+j]   B: K[n=ni*16+lr][k=...]
  short8 qf[4], kf[4];
#pragma unroll
  for (int mi = 0; mi < 4; ++mi) {
    const int row = mi * 16 + lr;
    qf[mi] = (row < 49)
        ? *(const short8*)&qkv[base + (size_t)row * 1152 + h * 32 + quad * 8] : z8;
  }
#pragma unroll
  for (int ni = 0; ni < 4; ++ni) {
    const int tok = ni * 16 + lr;
    kf[ni] = (tok < 49)
        ? *(const short8*)&qkv[base + (size_t)tok * 1152 + 384 + h * 32 + quad * 8] : z8;
  }
  f32x4 s[4][4] = {};
#pragma unroll
  for (int mi = 0; mi < 4; ++mi)
#pragma unroll
    for (int ni = 0; ni < 4; ++ni)
      s[mi][ni] = __builtin_amdgcn_mfma_f32_16x16x32_bf16(qf[mi], kf[ni], s[mi][ni], 0, 0, 0);

  // ---- bias + mask + softmax (quad-local rows), P -> LDS bf16 (swizzled) ----
  const float* rh = &rpbf[h * 2401];
  const float* mw = &mask[(size_t)(b & 63) * 2401];
  float linv[4][4];
#pragma unroll
  for (int mi = 0; mi < 4; ++mi) {
#pragma unroll
    for (int r = 0; r < 4; ++r) {
      const int row = mi * 16 + quad * 4 + r;
      float vals[4];
#pragma unroll
      for (int ni = 0; ni < 4; ++ni) {
        const int col = ni * 16 + lr;
        float v;
        if (row < 49 && col < 49)
          v = s[mi][ni][r] + rh[row * 49 + col] + mw[row * 49 + col];
        else
          v = -1e30f;                 // finite: pad rows -> exp(0), never output
        vals[ni] = v;
      }
      float m = fmaxf(fmaxf(vals[0], vals[1]), fmaxf(vals[2], vals[3]));
      m = fmaxf(m, __shfl_xor(m, 1));
      m = fmaxf(m, __shfl_xor(m, 2));
      m = fmaxf(m, __shfl_xor(m, 4));
      m = fmaxf(m, __shfl_xor(m, 8));
      float l = 0.f;
#pragma unroll
      for (int ni = 0; ni < 4; ++ni) {
        const float p = __expf(vals[ni] - m);
        l += p;
        const int col = ni * 16 + lr;
        P[row * 64 + (((col >> 3) ^ (row & 7)) * 8) + (col & 7)] = f2bf(p);
      }
      l += __shfl_xor(l, 1);
      l += __shfl_xor(l, 2);
      l += __shfl_xor(l, 4);
      l += __shfl_xor(l, 8);
      linv[mi][r] = 1.0f / l;
    }
  }

  // ---- O = P @ V ----
  f32x4 o[4][2] = {};
#pragma unroll
  for (int kh = 0; kh < 2; ++kh) {
    const int chunk = (kh * 4 + quad) ^ (lr & 7);   // row&7 == lr&7 for both
    short8 vf[2];
#pragma unroll
    for (int ni = 0; ni < 2; ++ni)
      vf[ni] = *(const short8*)&Vt[(ni * 16 + lr) * 64 + chunk * 8];
#pragma unroll
    for (int mi = 0; mi < 4; ++mi) {
      short8 pf = *(const short8*)&P[(mi * 16 + lr) * 64 + chunk * 8];
#pragma unroll
      for (int ni = 0; ni < 2; ++ni)
        o[mi][ni] = __builtin_amdgcn_mfma_f32_16x16x32_bf16(pf, vf[ni], o[mi][ni], 0, 0, 0);
    }
  }

  // ---- epilogue: attnout[b][row][h*32+d] = O/l, bf16 ----
  u16* outp = attnout + (size_t)b * (49 * 384) + h * 32;
#pragma unroll
  for (int mi = 0; mi < 4; ++mi)
#pragma unroll
    for (int r = 0; r < 4; ++r) {
      const int row = mi * 16 + quad * 4 + r;
      if (row < 49) {
        const float li = linv[mi][r];
#pragma unroll
        for (int ni = 0; ni < 2; ++ni)
          outp[row * 384 + ni * 16 + lr] = f2bf(o[mi][ni][r] * li);
      }
    }
}

// ------------------------------------------------------------- launch -------
extern "C" void kernel_launch(void* const* d_in, const int* in_sizes, int n_in,
                              void* d_out, int out_size, void* d_ws, size_t ws_size,
                              hipStream_t stream) {
  const float* x      = (const float*)d_in[0];
  const float* mask   = (const float*)d_in[1];
  const float* qkv_w  = (const float*)d_in[2];
  const float* qkv_b  = (const float*)d_in[3];
  const float* proj_w = (const float*)d_in[4];
  const float* proj_b = (const float*)d_in[5];
  const float* rpb_t  = (const float*)d_in[6];
  float* out = (float*)d_out;

  // ws layout (618 MB + 4.6 KB bias_s).
  char* ws = (char*)d_ws;
  u16* qkv    = (u16*)ws;                                    // [200704][1152] bf16
  u16* xb     = (u16*)(ws + 462422016u);                     // [200704][384] bf16
  u16* attnout = xb;                                         // alias (xb dead)
  u16* wqb    = (u16*)(ws + 462422016u + 154140672u);        // [1152][384] bf16
  u16* wpb    = wqb + 442368;                                // [384][384] bf16
  float* rpbf = (float*)((char*)wpb + 294912u);              // [12][49][49] f32
  float* bias_s = (float*)((char*)rpbf + 115248u);           // [1152] f32 (scaled)

  prep_kernel<<<1096, 256, 0, stream>>>(x, qkv_w, proj_w, rpb_t, qkv_b,
                                        xb, wqb, wpb, rpbf, bias_s);
  gemm_nt<0><<<7056, 512, 0, stream>>>(xb, wqb, bias_s, (void*)qkv);
  attn_kernel<<<12288, 256, 0, stream>>>(qkv, mask, rpbf, attnout);
  gemm_nt<1><<<2352, 512, 0, stream>>>(attnout, wpb, proj_b, (void*)out);
}